// Round 1
// baseline (395.905 us; speedup 1.0000x reference)
//
#include <hip/hip_runtime.h>
#include <hip/hip_bf16.h>

// Problem constants (B=2, T=2048, D=768, E=8, H=1536, K=2)
#define NTOK 4096
#define DDIM 768
#define EEXP 8
#define HDIM 1536
#define CAP  8704          // 136 mblocks * 64 slots (worst-case padded pairs)
#define MAXMB 136

typedef float f32x4 __attribute__((ext_vector_type(4)));
typedef __bf16 bf16x8 __attribute__((ext_vector_type(8)));
typedef __bf16 bf16x4 __attribute__((ext_vector_type(4)));

// ---------------- workspace layout (bytes) ----------------
// xb   : bf16 x            [NTOK][DDIM]            6,291,456
// Gt   : bf16 gate_bank^T  [E][H][D]              18,874,368
// Ut   : bf16 up_bank^T    [E][H][D]              18,874,368
// Dt   : bf16 down_bank^T  [E][D][H]              18,874,368
// hbuf : bf16 h            [CAP][HDIM]            26,738,688
// topk_idx int[NTOK*2], topk_w float[NTOK*2]
// pair_token int[CAP], pair_w float[CAP]
// ctrl int[256]: [0..7]=counts [8..15]=offsets [16..23]=fillctr
//                [24]=total_mblocks [25]=padded_total [32..167]=mblock_expert
static const size_t XB_OFF   = 0;
static const size_t GT_OFF   = 6291456;
static const size_t UT_OFF   = GT_OFF + 18874368;
static const size_t DT_OFF   = UT_OFF + 18874368;
static const size_t H_OFF    = DT_OFF + 18874368;
static const size_t TKI_OFF  = H_OFF + 26738688;
static const size_t TKW_OFF  = TKI_OFF + NTOK*2*4;
static const size_t PT_OFF   = TKW_OFF + NTOK*2*4;
static const size_t PW_OFF   = PT_OFF + CAP*4;
static const size_t CTRL_OFF = PW_OFF + CAP*4;
static const size_t WS_NEEDED = CTRL_OFF + 1024;

// ---------------- kernels ----------------

__global__ __launch_bounds__(256) void convert_x_kernel(
    const float* __restrict__ x, __bf16* __restrict__ xb, int n4)
{
    int i = blockIdx.x * 256 + threadIdx.x;
    if (i < n4) {
        f32x4 v = reinterpret_cast<const f32x4*>(x)[i];
        bf16x4 o;
        o[0] = (__bf16)v[0]; o[1] = (__bf16)v[1];
        o[2] = (__bf16)v[2]; o[3] = (__bf16)v[3];
        reinterpret_cast<bf16x4*>(xb)[i] = o;
    }
}

// transpose last two dims + convert to bf16: src [z][R][C] f32 -> dst [z][C][R] bf16
__global__ __launch_bounds__(256) void transpose_bf16_kernel(
    const float* __restrict__ src, __bf16* __restrict__ dst, int R, int C)
{
    __shared__ float tile[32][33];
    const float* s = src + (size_t)blockIdx.z * R * C;
    __bf16* d = dst + (size_t)blockIdx.z * R * C;
    int tx = threadIdx.x & 31, ty = threadIdx.x >> 5;   // 32 x 8
    int r0 = blockIdx.y * 32, c0 = blockIdx.x * 32;
#pragma unroll
    for (int j = 0; j < 4; j++)
        tile[ty + j*8][tx] = s[(size_t)(r0 + ty + j*8) * C + c0 + tx];
    __syncthreads();
#pragma unroll
    for (int j = 0; j < 4; j++)
        d[(size_t)(c0 + ty + j*8) * R + r0 + tx] = (__bf16)tile[tx][ty + j*8];
}

__global__ __launch_bounds__(256) void init_pairs_kernel(
    int* __restrict__ pt, float* __restrict__ pw)
{
    int i = blockIdx.x * 256 + threadIdx.x;
    if (i < CAP) { pt[i] = 0; pw[i] = 0.0f; }
}

// one wave per token: 8 dots of length 768, softmax, top-2, normalized weights
__global__ __launch_bounds__(256) void gating_kernel(
    const float* __restrict__ x, const float* __restrict__ gw,
    int* __restrict__ topk_idx, float* __restrict__ topk_w, int* __restrict__ ctrl)
{
    int lane = threadIdx.x & 63;
    int t = blockIdx.x * 4 + (threadIdx.x >> 6);
    const float* xr = x + (size_t)t * DDIM;
    float acc[EEXP];
#pragma unroll
    for (int e = 0; e < EEXP; e++) acc[e] = 0.0f;
    for (int i = 0; i < DDIM / 64; i++) {
        int d = lane + i * 64;
        float xv = xr[d];
#pragma unroll
        for (int e = 0; e < EEXP; e++) acc[e] += xv * gw[e * DDIM + d];
    }
#pragma unroll
    for (int e = 0; e < EEXP; e++) {
        for (int off = 32; off; off >>= 1) acc[e] += __shfl_xor(acc[e], off);
    }
    if (lane == 0) {
        float m = acc[0];
#pragma unroll
        for (int e = 1; e < EEXP; e++) m = fmaxf(m, acc[e]);
        float p[EEXP], sum = 0.0f;
#pragma unroll
        for (int e = 0; e < EEXP; e++) { p[e] = expf(acc[e] - m); sum += p[e]; }
        int i0 = 0; float b0 = acc[0];
#pragma unroll
        for (int e = 1; e < EEXP; e++) if (acc[e] > b0) { b0 = acc[e]; i0 = e; }
        int i1 = -1; float b1 = -3.4e38f;
#pragma unroll
        for (int e = 0; e < EEXP; e++) if (e != i0 && acc[e] > b1) { b1 = acc[e]; i1 = e; }
        float pr0 = p[i0] / sum, pr1 = p[i1] / sum;
        float den = pr0 + pr1 + 1e-8f;
        topk_idx[2*t]   = i0; topk_w[2*t]   = pr0 / den;
        topk_idx[2*t+1] = i1; topk_w[2*t+1] = pr1 / den;
        atomicAdd(&ctrl[i0], 1);
        atomicAdd(&ctrl[i1], 1);
    }
}

__global__ void scan_kernel(int* __restrict__ ctrl)
{
    if (threadIdx.x == 0 && blockIdx.x == 0) {
        int off = 0, gmb = 0;
        for (int e = 0; e < EEXP; e++) {
            ctrl[8 + e] = off;
            int nmb = (ctrl[e] + 63) >> 6;
            for (int i = 0; i < nmb; i++) ctrl[32 + gmb++] = e;
            off += nmb << 6;
        }
        ctrl[24] = gmb;
        ctrl[25] = off;
    }
}

__global__ __launch_bounds__(256) void fill_kernel(
    const int* __restrict__ topk_idx, const float* __restrict__ topk_w,
    int* __restrict__ ctrl, int* __restrict__ pt, float* __restrict__ pw)
{
    int t = blockIdx.x * 256 + threadIdx.x;
    if (t < NTOK) {
#pragma unroll
        for (int k = 0; k < 2; k++) {
            int e = topk_idx[2*t + k];
            int pos = atomicAdd(&ctrl[16 + e], 1);
            int slot = ctrl[8 + e] + pos;
            pt[slot] = t;
            pw[slot] = topk_w[2*t + k];
        }
    }
}

// gate/up fused GEMM: per mblock (64 pairs) x 128 h-cols, K=768
// h = silu(x @ G) * (x @ U), stored bf16
__global__ __launch_bounds__(256) void gateup_kernel(
    const __bf16* __restrict__ xb, const __bf16* __restrict__ Gt,
    const __bf16* __restrict__ Ut, const int* __restrict__ ctrl,
    const int* __restrict__ pair_token, __bf16* __restrict__ hbuf)
{
    int mb = blockIdx.x;
    if (mb >= ctrl[24]) return;
    int e = ctrl[32 + mb];
    int hbase = blockIdx.y * 128;
    const __bf16* G = Gt + (size_t)e * HDIM * DDIM;   // [H][D]
    const __bf16* U = Ut + (size_t)e * HDIM * DDIM;

    __shared__ __bf16 As[64][40];
    __shared__ __bf16 Bg[128][40];
    __shared__ __bf16 Bu[128][40];

    int tid = threadIdx.x;
    int lane = tid & 63, wave = tid >> 6;
    int wr = wave >> 1, wc = wave & 1;

    int arow = tid >> 2, akseg = (tid & 3) * 8;
    int atok = pair_token[mb * 64 + arow];
    const __bf16* aptr = xb + (size_t)atok * DDIM + akseg;

    int bn = tid >> 1, bkh = (tid & 1) * 16;
    const __bf16* gptr = G + (size_t)(hbase + bn) * DDIM + bkh;
    const __bf16* uptr = U + (size_t)(hbase + bn) * DDIM + bkh;

    f32x4 accg[2][4], accu[2][4];
#pragma unroll
    for (int m = 0; m < 2; m++)
#pragma unroll
        for (int n = 0; n < 4; n++) { accg[m][n] = (f32x4)0.0f; accu[m][n] = (f32x4)0.0f; }

    for (int kk = 0; kk < DDIM; kk += 32) {
        *reinterpret_cast<bf16x8*>(&As[arow][akseg]) =
            *reinterpret_cast<const bf16x8*>(aptr + kk);
        *reinterpret_cast<bf16x8*>(&Bg[bn][bkh]) =
            *reinterpret_cast<const bf16x8*>(gptr + kk);
        *reinterpret_cast<bf16x8*>(&Bg[bn][bkh + 8]) =
            *reinterpret_cast<const bf16x8*>(gptr + kk + 8);
        *reinterpret_cast<bf16x8*>(&Bu[bn][bkh]) =
            *reinterpret_cast<const bf16x8*>(uptr + kk);
        *reinterpret_cast<bf16x8*>(&Bu[bn][bkh + 8]) =
            *reinterpret_cast<const bf16x8*>(uptr + kk + 8);
        __syncthreads();

        bf16x8 af[2];
#pragma unroll
        for (int m = 0; m < 2; m++)
            af[m] = *reinterpret_cast<const bf16x8*>(
                &As[wr*32 + m*16 + (lane & 15)][(lane >> 4) * 8]);
#pragma unroll
        for (int n = 0; n < 4; n++) {
            bf16x8 bg = *reinterpret_cast<const bf16x8*>(
                &Bg[wc*64 + n*16 + (lane & 15)][(lane >> 4) * 8]);
            bf16x8 bu = *reinterpret_cast<const bf16x8*>(
                &Bu[wc*64 + n*16 + (lane & 15)][(lane >> 4) * 8]);
#pragma unroll
            for (int m = 0; m < 2; m++) {
                accg[m][n] = __builtin_amdgcn_mfma_f32_16x16x32_bf16(af[m], bg, accg[m][n], 0, 0, 0);
                accu[m][n] = __builtin_amdgcn_mfma_f32_16x16x32_bf16(af[m], bu, accu[m][n], 0, 0, 0);
            }
        }
        __syncthreads();
    }

    size_t slotbase = (size_t)mb * 64;
#pragma unroll
    for (int m = 0; m < 2; m++)
#pragma unroll
        for (int n = 0; n < 4; n++)
#pragma unroll
            for (int r = 0; r < 4; r++) {
                int row = wr*32 + m*16 + (lane >> 4) * 4 + r;
                int col = hbase + wc*64 + n*16 + (lane & 15);
                float a = accg[m][n][r], u = accu[m][n][r];
                float hv = (a / (1.0f + expf(-a))) * u;
                hbuf[(slotbase + row) * HDIM + col] = (__bf16)hv;
            }
}

// down GEMM: y[pair, dcols] = h[pair, :] @ Dn ; epilogue atomicAdd(w * y) into out
__global__ __launch_bounds__(256) void down_kernel(
    const __bf16* __restrict__ hbuf, const __bf16* __restrict__ Dt,
    const int* __restrict__ ctrl, const int* __restrict__ pair_token,
    const float* __restrict__ pair_w, float* __restrict__ out)
{
    int mb = blockIdx.x;
    if (mb >= ctrl[24]) return;
    int e = ctrl[32 + mb];
    int dbase = blockIdx.y * 128;
    const __bf16* Dn = Dt + (size_t)e * DDIM * HDIM;   // [D][H]

    __shared__ __bf16 As[64][40];
    __shared__ __bf16 Bd[128][40];

    int tid = threadIdx.x;
    int lane = tid & 63, wave = tid >> 6;
    int wr = wave >> 1, wc = wave & 1;

    int arow = tid >> 2, akseg = (tid & 3) * 8;
    const __bf16* aptr = hbuf + (size_t)(mb * 64 + arow) * HDIM + akseg;

    int bn = tid >> 1, bkh = (tid & 1) * 16;
    const __bf16* bptr = Dn + (size_t)(dbase + bn) * HDIM + bkh;

    f32x4 acc[2][4];
#pragma unroll
    for (int m = 0; m < 2; m++)
#pragma unroll
        for (int n = 0; n < 4; n++) acc[m][n] = (f32x4)0.0f;

    for (int kk = 0; kk < HDIM; kk += 32) {
        *reinterpret_cast<bf16x8*>(&As[arow][akseg]) =
            *reinterpret_cast<const bf16x8*>(aptr + kk);
        *reinterpret_cast<bf16x8*>(&Bd[bn][bkh]) =
            *reinterpret_cast<const bf16x8*>(bptr + kk);
        *reinterpret_cast<bf16x8*>(&Bd[bn][bkh + 8]) =
            *reinterpret_cast<const bf16x8*>(bptr + kk + 8);
        __syncthreads();

        bf16x8 af[2];
#pragma unroll
        for (int m = 0; m < 2; m++)
            af[m] = *reinterpret_cast<const bf16x8*>(
                &As[wr*32 + m*16 + (lane & 15)][(lane >> 4) * 8]);
#pragma unroll
        for (int n = 0; n < 4; n++) {
            bf16x8 bd = *reinterpret_cast<const bf16x8*>(
                &Bd[wc*64 + n*16 + (lane & 15)][(lane >> 4) * 8]);
#pragma unroll
            for (int m = 0; m < 2; m++)
                acc[m][n] = __builtin_amdgcn_mfma_f32_16x16x32_bf16(af[m], bd, acc[m][n], 0, 0, 0);
        }
        __syncthreads();
    }

#pragma unroll
    for (int m = 0; m < 2; m++)
#pragma unroll
        for (int n = 0; n < 4; n++)
#pragma unroll
            for (int r = 0; r < 4; r++) {
                int row = wr*32 + m*16 + (lane >> 4) * 4 + r;
                int slot = mb * 64 + row;
                int t = pair_token[slot];
                float w = pair_w[slot];
                int col = dbase + wc*64 + n*16 + (lane & 15);
                atomicAdd(&out[(size_t)t * DDIM + col], acc[m][n][r] * w);
            }
}

// ---------------- launch ----------------
extern "C" void kernel_launch(void* const* d_in, const int* in_sizes, int n_in,
                              void* d_out, int out_size, void* d_ws, size_t ws_size,
                              hipStream_t stream)
{
    if (ws_size < WS_NEEDED) return;   // clean failure signal if scratch too small

    const float* x      = (const float*)d_in[0];
    const float* gate_w = (const float*)d_in[1];
    const float* gbank  = (const float*)d_in[2];
    const float* ubank  = (const float*)d_in[3];
    const float* dbank  = (const float*)d_in[4];
    float* out = (float*)d_out;

    char* ws = (char*)d_ws;
    __bf16* xb   = (__bf16*)(ws + XB_OFF);
    __bf16* Gt   = (__bf16*)(ws + GT_OFF);
    __bf16* Ut   = (__bf16*)(ws + UT_OFF);
    __bf16* Dt   = (__bf16*)(ws + DT_OFF);
    __bf16* hbuf = (__bf16*)(ws + H_OFF);
    int*    tki  = (int*)(ws + TKI_OFF);
    float*  tkw  = (float*)(ws + TKW_OFF);
    int*    pt   = (int*)(ws + PT_OFF);
    float*  pw   = (float*)(ws + PW_OFF);
    int*    ctrl = (int*)(ws + CTRL_OFF);

    hipMemsetAsync(d_out, 0, (size_t)out_size * sizeof(float), stream);
    hipMemsetAsync(ctrl, 0, 1024, stream);

    convert_x_kernel<<<(NTOK * DDIM / 4 + 255) / 256, 256, 0, stream>>>(x, xb, NTOK * DDIM / 4);

    // gate_bank [E][768][1536] -> Gt [E][1536][768]
    transpose_bf16_kernel<<<dim3(HDIM/32, DDIM/32, EEXP), 256, 0, stream>>>(gbank, Gt, DDIM, HDIM);
    transpose_bf16_kernel<<<dim3(HDIM/32, DDIM/32, EEXP), 256, 0, stream>>>(ubank, Ut, DDIM, HDIM);
    // down_bank [E][1536][768] -> Dt [E][768][1536]
    transpose_bf16_kernel<<<dim3(DDIM/32, HDIM/32, EEXP), 256, 0, stream>>>(dbank, Dt, HDIM, DDIM);

    init_pairs_kernel<<<(CAP + 255) / 256, 256, 0, stream>>>(pt, pw);
    gating_kernel<<<NTOK / 4, 256, 0, stream>>>(x, gate_w, tki, tkw, ctrl);
    scan_kernel<<<1, 64, 0, stream>>>(ctrl);
    fill_kernel<<<NTOK / 256, 256, 0, stream>>>(tki, tkw, ctrl, pt, pw);

    gateup_kernel<<<dim3(MAXMB, HDIM / 128), 256, 0, stream>>>(xb, Gt, Ut, ctrl, pt, hbuf);
    down_kernel<<<dim3(MAXMB, DDIM / 128), 256, 0, stream>>>(hbuf, Dt, ctrl, pt, pw, out);
}

// Round 2
// 326.135 us; speedup vs baseline: 1.2139x; 1.2139x over previous
//
#include <hip/hip_runtime.h>
#include <hip/hip_bf16.h>

// Problem constants (B=2, T=2048, D=768, E=8, H=1536, K=2)
#define NTOK 4096
#define DDIM 768
#define EEXP 8
#define HDIM 1536
#define MBLK 128
#define MAXMB 72            // floor(8192/128) + 8 experts of padding
#define CAP  (MAXMB * MBLK) // 9216

typedef float f32x4 __attribute__((ext_vector_type(4)));
typedef __bf16 bf16x8 __attribute__((ext_vector_type(8)));
typedef __bf16 bf16x4 __attribute__((ext_vector_type(4)));

// ---------------- workspace layout (bytes) ----------------
static const size_t XB_OFF   = 0;                       // bf16 x [NTOK][D]      6,291,456
static const size_t GT_OFF   = 6291456;                 // bf16 Gt [E][H][D]    18,874,368
static const size_t UT_OFF   = GT_OFF + 18874368;       // bf16 Ut [E][H][D]    18,874,368
static const size_t YB_OFF   = GT_OFF;                  // f32 ybuf [CAP][D]    28,311,552 (aliases Gt+Ut, dead after gateup)
static const size_t DT_OFF   = UT_OFF + 18874368;       // bf16 Dt [E][D][H]    18,874,368
static const size_t HB_OFF   = DT_OFF + 18874368;       // bf16 h  [CAP][H]     28,311,552
static const size_t TKI_OFF  = HB_OFF + 28311552;       // int  topk_idx [NTOK*2]
static const size_t TKW_OFF  = TKI_OFF + NTOK*2*4;      // f32  topk_w   [NTOK*2]
static const size_t PT_OFF   = TKW_OFF + NTOK*2*4;      // int  pair_token [CAP]
static const size_t SL_OFF   = PT_OFF + CAP*4;          // int  slot_of  [NTOK*2]
static const size_t CTRL_OFF = SL_OFF + NTOK*2*4;
static const size_t WS_NEEDED = CTRL_OFF + 1024;

#define GLOAD16(g, l) __builtin_amdgcn_global_load_lds( \
    (const __attribute__((address_space(1))) void*)(g),  \
    (__attribute__((address_space(3))) void*)(l), 16, 0, 0)

// ---------------- small kernels ----------------

__global__ __launch_bounds__(256) void convert_x_kernel(
    const float* __restrict__ x, __bf16* __restrict__ xb, int n4)
{
    int i = blockIdx.x * 256 + threadIdx.x;
    if (i < n4) {
        f32x4 v = reinterpret_cast<const f32x4*>(x)[i];
        bf16x4 o;
        o[0] = (__bf16)v[0]; o[1] = (__bf16)v[1];
        o[2] = (__bf16)v[2]; o[3] = (__bf16)v[3];
        reinterpret_cast<bf16x4*>(xb)[i] = o;
    }
}

// transpose last two dims + convert to bf16: src [z][R][C] f32 -> dst [z][C][R] bf16
__global__ __launch_bounds__(256) void transpose_bf16_kernel(
    const float* __restrict__ src, __bf16* __restrict__ dst, int R, int C)
{
    __shared__ float tile[32][33];
    const float* s = src + (size_t)blockIdx.z * R * C;
    __bf16* d = dst + (size_t)blockIdx.z * R * C;
    int tx = threadIdx.x & 31, ty = threadIdx.x >> 5;   // 32 x 8
    int r0 = blockIdx.y * 32, c0 = blockIdx.x * 32;
#pragma unroll
    for (int j = 0; j < 4; j++)
        tile[ty + j*8][tx] = s[(size_t)(r0 + ty + j*8) * C + c0 + tx];
    __syncthreads();
#pragma unroll
    for (int j = 0; j < 4; j++)
        d[(size_t)(c0 + ty + j*8) * R + r0 + tx] = (__bf16)tile[tx][ty + j*8];
}

__global__ __launch_bounds__(256) void init_pairs_kernel(int* __restrict__ pt)
{
    int i = blockIdx.x * 256 + threadIdx.x;
    if (i < CAP) pt[i] = 0;
}

// one wave per token: 8 dots of length 768, softmax, top-2, normalized weights
__global__ __launch_bounds__(256) void gating_kernel(
    const float* __restrict__ x, const float* __restrict__ gw,
    int* __restrict__ topk_idx, float* __restrict__ topk_w, int* __restrict__ ctrl)
{
    int lane = threadIdx.x & 63;
    int t = blockIdx.x * 4 + (threadIdx.x >> 6);
    const float* xr = x + (size_t)t * DDIM;
    float acc[EEXP];
#pragma unroll
    for (int e = 0; e < EEXP; e++) acc[e] = 0.0f;
    for (int i = 0; i < DDIM / 64; i++) {
        int d = lane + i * 64;
        float xv = xr[d];
#pragma unroll
        for (int e = 0; e < EEXP; e++) acc[e] += xv * gw[e * DDIM + d];
    }
#pragma unroll
    for (int e = 0; e < EEXP; e++) {
        for (int off = 32; off; off >>= 1) acc[e] += __shfl_xor(acc[e], off);
    }
    if (lane == 0) {
        float m = acc[0];
#pragma unroll
        for (int e = 1; e < EEXP; e++) m = fmaxf(m, acc[e]);
        float p[EEXP], sum = 0.0f;
#pragma unroll
        for (int e = 0; e < EEXP; e++) { p[e] = expf(acc[e] - m); sum += p[e]; }
        int i0 = 0; float b0 = acc[0];
#pragma unroll
        for (int e = 1; e < EEXP; e++) if (acc[e] > b0) { b0 = acc[e]; i0 = e; }
        int i1 = -1; float b1 = -3.4e38f;
#pragma unroll
        for (int e = 0; e < EEXP; e++) if (e != i0 && acc[e] > b1) { b1 = acc[e]; i1 = e; }
        float pr0 = p[i0] / sum, pr1 = p[i1] / sum;
        float den = pr0 + pr1 + 1e-8f;
        topk_idx[2*t]   = i0; topk_w[2*t]   = pr0 / den;
        topk_idx[2*t+1] = i1; topk_w[2*t+1] = pr1 / den;
        atomicAdd(&ctrl[i0], 1);
        atomicAdd(&ctrl[i1], 1);
    }
}

__global__ void scan_kernel(int* __restrict__ ctrl)
{
    if (threadIdx.x == 0 && blockIdx.x == 0) {
        int off = 0, gmb = 0;
        for (int e = 0; e < EEXP; e++) {
            ctrl[8 + e] = off;
            int nmb = (ctrl[e] + MBLK - 1) >> 7;
            for (int i = 0; i < nmb; i++) ctrl[32 + gmb++] = e;
            off += nmb << 7;
        }
        ctrl[24] = gmb;
    }
}

__global__ __launch_bounds__(256) void fill_kernel(
    const int* __restrict__ topk_idx, const float* __restrict__ topk_w,
    int* __restrict__ ctrl, int* __restrict__ pt, int* __restrict__ slot_of)
{
    int t = blockIdx.x * 256 + threadIdx.x;
    if (t < NTOK) {
#pragma unroll
        for (int k = 0; k < 2; k++) {
            int e = topk_idx[2*t + k];
            int pos = atomicAdd(&ctrl[16 + e], 1);
            int slot = ctrl[8 + e] + pos;
            pt[slot] = t;
            slot_of[2*t + k] = slot;
        }
    }
}

// ---------------- gate/up fused GEMM (m97 structure) ----------------
// Tile: 128 pairs x 64 h-cols, BK=64, K=768. 4 waves (2x2), wave tile 64x32.
// h = silu(x@G) * (x@U) stored bf16 to hbuf.
__global__ __launch_bounds__(256) void gateup_kernel(
    const __bf16* __restrict__ xb, const __bf16* __restrict__ Gt,
    const __bf16* __restrict__ Ut, const int* __restrict__ ctrl,
    const int* __restrict__ pair_token, __bf16* __restrict__ hbuf)
{
    int mb = blockIdx.x;
    if (mb >= ctrl[24]) return;
    int e = ctrl[32 + mb];
    int hbase = blockIdx.y * 64;
    const __bf16* G = Gt + (size_t)e * HDIM * DDIM;   // [H][D]
    const __bf16* U = Ut + (size_t)e * HDIM * DDIM;

    __shared__ __bf16 As[128 * 64];   // 16 KB, linear [row][64k]
    __shared__ __bf16 Bg[64 * 64];    //  8 KB
    __shared__ __bf16 Bu[64 * 64];    //  8 KB

    int tid = threadIdx.x;
    int lane = tid & 63, w = tid >> 6;
    int wr = w >> 1, wc = w & 1;

    // staging addresses: chunk = 1024B = 8 rows of 128B; lane covers 16B
    int lr = lane >> 3, lc = (lane & 7) * 8;  // row-in-chunk, col elem
    const __bf16* gA[4];
#pragma unroll
    for (int j = 0; j < 4; j++) {
        int c = w * 4 + j;
        int row = c * 8 + lr;
        int tok = pair_token[mb * MBLK + row];
        gA[j] = xb + (size_t)tok * DDIM + lc;
    }
    const __bf16* gG[2]; const __bf16* gU[2];
#pragma unroll
    for (int j = 0; j < 2; j++) {
        int c = w * 2 + j;
        int row = c * 8 + lr;
        gG[j] = G + (size_t)(hbase + row) * DDIM + lc;
        gU[j] = U + (size_t)(hbase + row) * DDIM + lc;
    }

    f32x4 accg[4][2], accu[4][2];
#pragma unroll
    for (int m = 0; m < 4; m++)
#pragma unroll
        for (int n = 0; n < 2; n++) { accg[m][n] = (f32x4)0.0f; accu[m][n] = (f32x4)0.0f; }

    for (int kk = 0; kk < DDIM; kk += 64) {
#pragma unroll
        for (int j = 0; j < 4; j++) {
            int c = w * 4 + j;
            GLOAD16(gA[j] + kk, &As[c * 512 + lane * 8]);
        }
#pragma unroll
        for (int j = 0; j < 2; j++) {
            int c = w * 2 + j;
            GLOAD16(gG[j] + kk, &Bg[c * 512 + lane * 8]);
            GLOAD16(gU[j] + kk, &Bu[c * 512 + lane * 8]);
        }
        __syncthreads();   // drains vmcnt before reads

#pragma unroll
        for (int ks = 0; ks < 2; ks++) {
            int kb = ks * 32 + (lane >> 4) * 8;
            bf16x8 af[4];
#pragma unroll
            for (int m = 0; m < 4; m++)
                af[m] = *reinterpret_cast<const bf16x8*>(
                    &As[(wr * 64 + m * 16 + (lane & 15)) * 64 + kb]);
#pragma unroll
            for (int n = 0; n < 2; n++) {
                bf16x8 bg = *reinterpret_cast<const bf16x8*>(
                    &Bg[(wc * 32 + n * 16 + (lane & 15)) * 64 + kb]);
                bf16x8 bu = *reinterpret_cast<const bf16x8*>(
                    &Bu[(wc * 32 + n * 16 + (lane & 15)) * 64 + kb]);
#pragma unroll
                for (int m = 0; m < 4; m++) {
                    accg[m][n] = __builtin_amdgcn_mfma_f32_16x16x32_bf16(af[m], bg, accg[m][n], 0, 0, 0);
                    accu[m][n] = __builtin_amdgcn_mfma_f32_16x16x32_bf16(af[m], bu, accu[m][n], 0, 0, 0);
                }
            }
        }
        __syncthreads();
    }

    size_t slotbase = (size_t)mb * MBLK;
#pragma unroll
    for (int m = 0; m < 4; m++)
#pragma unroll
        for (int n = 0; n < 2; n++)
#pragma unroll
            for (int r = 0; r < 4; r++) {
                int row = wr * 64 + m * 16 + (lane >> 4) * 4 + r;
                int col = hbase + wc * 32 + n * 16 + (lane & 15);
                float a = accg[m][n][r], u = accu[m][n][r];
                float hv = (a / (1.0f + expf(-a))) * u;
                hbuf[(slotbase + row) * HDIM + col] = (__bf16)hv;
            }
}

// ---------------- down GEMM (m97 structure) ----------------
// Tile: 128 pairs x 64 d-cols, BK=64, K=1536. Writes f32 ybuf[slot][D].
__global__ __launch_bounds__(256) void down_kernel(
    const __bf16* __restrict__ hbuf, const __bf16* __restrict__ Dt,
    const int* __restrict__ ctrl, float* __restrict__ ybuf)
{
    int mb = blockIdx.x;
    if (mb >= ctrl[24]) return;
    int e = ctrl[32 + mb];
    int dbase = blockIdx.y * 64;
    const __bf16* Dn = Dt + (size_t)e * DDIM * HDIM;   // [D][H]

    __shared__ __bf16 As[128 * 64];   // 16 KB
    __shared__ __bf16 Bd[64 * 64];    //  8 KB

    int tid = threadIdx.x;
    int lane = tid & 63, w = tid >> 6;
    int wr = w >> 1, wc = w & 1;

    int lr = lane >> 3, lc = (lane & 7) * 8;
    const __bf16* gA[4];
#pragma unroll
    for (int j = 0; j < 4; j++) {
        int c = w * 4 + j;
        int row = c * 8 + lr;
        gA[j] = hbuf + (size_t)(mb * MBLK + row) * HDIM + lc;
    }
    const __bf16* gB[2];
#pragma unroll
    for (int j = 0; j < 2; j++) {
        int c = w * 2 + j;
        int row = c * 8 + lr;
        gB[j] = Dn + (size_t)(dbase + row) * HDIM + lc;
    }

    f32x4 acc[4][2];
#pragma unroll
    for (int m = 0; m < 4; m++)
#pragma unroll
        for (int n = 0; n < 2; n++) acc[m][n] = (f32x4)0.0f;

    for (int kk = 0; kk < HDIM; kk += 64) {
#pragma unroll
        for (int j = 0; j < 4; j++) {
            int c = w * 4 + j;
            GLOAD16(gA[j] + kk, &As[c * 512 + lane * 8]);
        }
#pragma unroll
        for (int j = 0; j < 2; j++) {
            int c = w * 2 + j;
            GLOAD16(gB[j] + kk, &Bd[c * 512 + lane * 8]);
        }
        __syncthreads();

#pragma unroll
        for (int ks = 0; ks < 2; ks++) {
            int kb = ks * 32 + (lane >> 4) * 8;
            bf16x8 af[4];
#pragma unroll
            for (int m = 0; m < 4; m++)
                af[m] = *reinterpret_cast<const bf16x8*>(
                    &As[(wr * 64 + m * 16 + (lane & 15)) * 64 + kb]);
#pragma unroll
            for (int n = 0; n < 2; n++) {
                bf16x8 bd = *reinterpret_cast<const bf16x8*>(
                    &Bd[(wc * 32 + n * 16 + (lane & 15)) * 64 + kb]);
#pragma unroll
                for (int m = 0; m < 4; m++)
                    acc[m][n] = __builtin_amdgcn_mfma_f32_16x16x32_bf16(af[m], bd, acc[m][n], 0, 0, 0);
            }
        }
        __syncthreads();
    }

#pragma unroll
    for (int m = 0; m < 4; m++)
#pragma unroll
        for (int n = 0; n < 2; n++)
#pragma unroll
            for (int r = 0; r < 4; r++) {
                int row = wr * 64 + m * 16 + (lane >> 4) * 4 + r;
                int col = dbase + wc * 32 + n * 16 + (lane & 15);
                ybuf[(size_t)(mb * MBLK + row) * DDIM + col] = acc[m][n][r];
            }
}

// combine: out[t] = w0*y[s0] + w1*y[s1]; fully overwrites d_out.
// one block per token, 192 threads x f32x4
__global__ __launch_bounds__(192) void combine_kernel(
    const float* __restrict__ ybuf, const int* __restrict__ slot_of,
    const float* __restrict__ topk_w, float* __restrict__ out)
{
    int t = blockIdx.x;
    int q = threadIdx.x;
    int s0 = slot_of[2*t], s1 = slot_of[2*t+1];
    float w0 = topk_w[2*t], w1 = topk_w[2*t+1];
    f32x4 y0 = reinterpret_cast<const f32x4*>(ybuf + (size_t)s0 * DDIM)[q];
    f32x4 y1 = reinterpret_cast<const f32x4*>(ybuf + (size_t)s1 * DDIM)[q];
    f32x4 o;
#pragma unroll
    for (int r = 0; r < 4; r++) o[r] = w0 * y0[r] + w1 * y1[r];
    reinterpret_cast<f32x4*>(out + (size_t)t * DDIM)[q] = o;
}

// ---------------- launch ----------------
extern "C" void kernel_launch(void* const* d_in, const int* in_sizes, int n_in,
                              void* d_out, int out_size, void* d_ws, size_t ws_size,
                              hipStream_t stream)
{
    if (ws_size < WS_NEEDED) return;

    const float* x      = (const float*)d_in[0];
    const float* gate_w = (const float*)d_in[1];
    const float* gbank  = (const float*)d_in[2];
    const float* ubank  = (const float*)d_in[3];
    const float* dbank  = (const float*)d_in[4];
    float* out = (float*)d_out;

    char* ws = (char*)d_ws;
    __bf16* xb   = (__bf16*)(ws + XB_OFF);
    __bf16* Gt   = (__bf16*)(ws + GT_OFF);
    __bf16* Ut   = (__bf16*)(ws + UT_OFF);
    float*  ybuf = (float*)(ws + YB_OFF);
    __bf16* Dt   = (__bf16*)(ws + DT_OFF);
    __bf16* hbuf = (__bf16*)(ws + HB_OFF);
    int*    tki  = (int*)(ws + TKI_OFF);
    float*  tkw  = (float*)(ws + TKW_OFF);
    int*    pt   = (int*)(ws + PT_OFF);
    int*    slot = (int*)(ws + SL_OFF);
    int*    ctrl = (int*)(ws + CTRL_OFF);

    hipMemsetAsync(ctrl, 0, 1024, stream);

    convert_x_kernel<<<(NTOK * DDIM / 4 + 255) / 256, 256, 0, stream>>>(x, xb, NTOK * DDIM / 4);

    // gate_bank [E][768][1536] -> Gt [E][1536][768]
    transpose_bf16_kernel<<<dim3(HDIM/32, DDIM/32, EEXP), 256, 0, stream>>>(gbank, Gt, DDIM, HDIM);
    transpose_bf16_kernel<<<dim3(HDIM/32, DDIM/32, EEXP), 256, 0, stream>>>(ubank, Ut, DDIM, HDIM);
    // down_bank [E][1536][768] -> Dt [E][768][1536]
    transpose_bf16_kernel<<<dim3(DDIM/32, HDIM/32, EEXP), 256, 0, stream>>>(dbank, Dt, HDIM, DDIM);

    init_pairs_kernel<<<(CAP + 255) / 256, 256, 0, stream>>>(pt);
    gating_kernel<<<NTOK / 4, 256, 0, stream>>>(x, gate_w, tki, tkw, ctrl);
    scan_kernel<<<1, 64, 0, stream>>>(ctrl);
    fill_kernel<<<NTOK / 256, 256, 0, stream>>>(tki, tkw, ctrl, pt, slot);

    gateup_kernel<<<dim3(MAXMB, HDIM / 64), 256, 0, stream>>>(xb, Gt, Ut, ctrl, pt, hbuf);
    down_kernel<<<dim3(MAXMB, DDIM / 64), 256, 0, stream>>>(hbuf, Dt, ctrl, ybuf);
    combine_kernel<<<NTOK, 192, 0, stream>>>(ybuf, slot, tkw, out);
}

// Round 3
// 185.683 us; speedup vs baseline: 2.1322x; 1.7564x over previous
//
#include <hip/hip_runtime.h>
#include <hip/hip_bf16.h>

// Problem constants (B=2, T=2048, D=768, E=8, H=1536, K=2)
#define NTOK 4096
#define DDIM 768
#define EEXP 8
#define HDIM 1536
#define MBLK 128
#define MAXMB 72            // floor(8192/128) + 8 experts of padding
#define CAP  (MAXMB * MBLK) // 9216
#define NENT (NTOK * 2)     // 8192 routed (token,k) entries
#define RTHREADS 1024
#define EPT (NENT / RTHREADS) // 8 entries per route thread

typedef float f32x4 __attribute__((ext_vector_type(4)));
typedef __bf16 bf16x8 __attribute__((ext_vector_type(8)));
typedef __bf16 bf16x4 __attribute__((ext_vector_type(4)));

// ---------------- workspace layout (bytes) ----------------
static const size_t XB_OFF   = 0;                       // bf16 x [NTOK][D]      6,291,456
static const size_t GT_OFF   = 6291456;                 // bf16 Gt [E][H][D]    18,874,368
static const size_t UT_OFF   = GT_OFF + 18874368;       // bf16 Ut [E][H][D]    18,874,368
static const size_t YB_OFF   = GT_OFF;                  // f32 ybuf [CAP][D]    28,311,552 (aliases Gt+Ut, dead after gateup)
static const size_t DT_OFF   = UT_OFF + 18874368;       // bf16 Dt [E][D][H]    18,874,368
static const size_t HB_OFF   = DT_OFF + 18874368;       // bf16 h  [CAP][H]     28,311,552
static const size_t TKI_OFF  = HB_OFF + 28311552;       // int  topk_idx [NENT]
static const size_t TKW_OFF  = TKI_OFF + NENT*4;        // f32  topk_w   [NENT]
static const size_t PT_OFF   = TKW_OFF + NENT*4;        // int  pair_token [CAP]
static const size_t SL_OFF   = PT_OFF + CAP*4;          // int  slot_of  [NENT]
static const size_t CTRL_OFF = SL_OFF + NENT*4;
static const size_t WS_NEEDED = CTRL_OFF + 1024;

#define GLOAD16(g, l) __builtin_amdgcn_global_load_lds( \
    (const __attribute__((address_space(1))) void*)(g),  \
    (__attribute__((address_space(3))) void*)(l), 16, 0, 0)

// ---------------- small kernels ----------------

__global__ __launch_bounds__(256) void convert_x_kernel(
    const float* __restrict__ x, __bf16* __restrict__ xb, int n4)
{
    int i = blockIdx.x * 256 + threadIdx.x;
    if (i < n4) {
        f32x4 v = reinterpret_cast<const f32x4*>(x)[i];
        bf16x4 o;
        o[0] = (__bf16)v[0]; o[1] = (__bf16)v[1];
        o[2] = (__bf16)v[2]; o[3] = (__bf16)v[3];
        reinterpret_cast<bf16x4*>(xb)[i] = o;
    }
}

// transpose last two dims + convert to bf16: src [z][R][C] f32 -> dst [z][C][R] bf16
__global__ __launch_bounds__(256) void transpose_bf16_kernel(
    const float* __restrict__ src, __bf16* __restrict__ dst, int R, int C)
{
    __shared__ float tile[32][33];
    const float* s = src + (size_t)blockIdx.z * R * C;
    __bf16* d = dst + (size_t)blockIdx.z * R * C;
    int tx = threadIdx.x & 31, ty = threadIdx.x >> 5;   // 32 x 8
    int r0 = blockIdx.y * 32, c0 = blockIdx.x * 32;
#pragma unroll
    for (int j = 0; j < 4; j++)
        tile[ty + j*8][tx] = s[(size_t)(r0 + ty + j*8) * C + c0 + tx];
    __syncthreads();
#pragma unroll
    for (int j = 0; j < 4; j++)
        d[(size_t)(c0 + ty + j*8) * R + r0 + tx] = (__bf16)tile[tx][ty + j*8];
}

__global__ __launch_bounds__(256) void init_pairs_kernel(int* __restrict__ pt)
{
    int i = blockIdx.x * 256 + threadIdx.x;
    if (i < CAP) pt[i] = 0;
}

// one wave per token: 8 dots of length 768, softmax, top-2, normalized weights.
// NO atomics (they serialized on 8 addresses: 101us -> counts now derived in route_kernel).
__global__ __launch_bounds__(256) void gating_kernel(
    const float* __restrict__ x, const float* __restrict__ gw,
    int* __restrict__ topk_idx, float* __restrict__ topk_w)
{
    int lane = threadIdx.x & 63;
    int t = blockIdx.x * 4 + (threadIdx.x >> 6);
    const float* xr = x + (size_t)t * DDIM;
    float acc[EEXP];
#pragma unroll
    for (int e = 0; e < EEXP; e++) acc[e] = 0.0f;
    for (int i = 0; i < DDIM / 64; i++) {
        int d = lane + i * 64;
        float xv = xr[d];
#pragma unroll
        for (int e = 0; e < EEXP; e++) acc[e] += xv * gw[e * DDIM + d];
    }
#pragma unroll
    for (int e = 0; e < EEXP; e++) {
        for (int off = 32; off; off >>= 1) acc[e] += __shfl_xor(acc[e], off);
    }
    if (lane == 0) {
        float m = acc[0];
#pragma unroll
        for (int e = 1; e < EEXP; e++) m = fmaxf(m, acc[e]);
        float p[EEXP], sum = 0.0f;
#pragma unroll
        for (int e = 0; e < EEXP; e++) { p[e] = expf(acc[e] - m); sum += p[e]; }
        int i0 = 0; float b0 = acc[0];
#pragma unroll
        for (int e = 1; e < EEXP; e++) if (acc[e] > b0) { b0 = acc[e]; i0 = e; }
        int i1 = -1; float b1 = -3.4e38f;
#pragma unroll
        for (int e = 0; e < EEXP; e++) if (e != i0 && acc[e] > b1) { b1 = acc[e]; i1 = e; }
        float pr0 = p[i0] / sum, pr1 = p[i1] / sum;
        float den = pr0 + pr1 + 1e-8f;
        topk_idx[2*t]   = i0; topk_w[2*t]   = pr0 / den;
        topk_idx[2*t+1] = i1; topk_w[2*t+1] = pr1 / den;
    }
}

// single-block deterministic routing: counts + 128-aligned offsets + mblock table
// + slot assignment, all via shfl/LDS prefix scans. Zero global atomics.
__global__ __launch_bounds__(RTHREADS) void route_kernel(
    const int* __restrict__ topk_idx, int* __restrict__ ctrl,
    int* __restrict__ pair_token, int* __restrict__ slot_of)
{
    __shared__ int wt[EEXP][16];    // per-wave totals
    __shared__ int wpre[EEXP][16];  // exclusive prefix of wave totals
    __shared__ int base[EEXP];      // 128-aligned expert base slot

    int tid = threadIdx.x;
    int lane = tid & 63, wv = tid >> 6;

    int e_of[EPT];
    int c[EEXP];
#pragma unroll
    for (int e = 0; e < EEXP; e++) c[e] = 0;
#pragma unroll
    for (int j = 0; j < EPT; j++) {
        int e = topk_idx[tid * EPT + j];
        e_of[j] = e;
        c[e]++;
    }

    // per-expert exclusive prefix within wave + wave total
    int pre[EEXP];
#pragma unroll
    for (int e = 0; e < EEXP; e++) {
        int v = c[e];
        for (int d = 1; d < 64; d <<= 1) {
            int u = __shfl_up(v, d);
            if (lane >= d) v += u;
        }
        pre[e] = v - c[e];
        if (lane == 63) wt[e][wv] = v;
    }
    __syncthreads();

    if (tid == 0) {
        int off = 0, gmb = 0;
        for (int e = 0; e < EEXP; e++) {
            int run = 0;
            for (int w = 0; w < 16; w++) { wpre[e][w] = run; run += wt[e][w]; }
            base[e] = off;
            int nmb = (run + MBLK - 1) >> 7;
            for (int i = 0; i < nmb; i++) ctrl[32 + gmb++] = e;
            off += nmb << 7;
        }
        ctrl[24] = gmb;
    }
    __syncthreads();

    int run[EEXP];
#pragma unroll
    for (int e = 0; e < EEXP; e++) run[e] = base[e] + wpre[e][wv] + pre[e];
#pragma unroll
    for (int j = 0; j < EPT; j++) {
        int ent = tid * EPT + j;
        int e = e_of[j];
        int slot = run[e]++;
        pair_token[slot] = ent >> 1;
        slot_of[ent] = slot;
    }
}

// ---------------- gate/up fused GEMM (m97 structure) ----------------
// Tile: 128 pairs x 64 h-cols, BK=64, K=768. 4 waves (2x2), wave tile 64x32.
// h = silu(x@G) * (x@U) stored bf16 to hbuf.
__global__ __launch_bounds__(256) void gateup_kernel(
    const __bf16* __restrict__ xb, const __bf16* __restrict__ Gt,
    const __bf16* __restrict__ Ut, const int* __restrict__ ctrl,
    const int* __restrict__ pair_token, __bf16* __restrict__ hbuf)
{
    int mb = blockIdx.x;
    if (mb >= ctrl[24]) return;
    int e = ctrl[32 + mb];
    int hbase = blockIdx.y * 64;
    const __bf16* G = Gt + (size_t)e * HDIM * DDIM;   // [H][D]
    const __bf16* U = Ut + (size_t)e * HDIM * DDIM;

    __shared__ __bf16 As[128 * 64];   // 16 KB, linear [row][64k]
    __shared__ __bf16 Bg[64 * 64];    //  8 KB
    __shared__ __bf16 Bu[64 * 64];    //  8 KB

    int tid = threadIdx.x;
    int lane = tid & 63, w = tid >> 6;
    int wr = w >> 1, wc = w & 1;

    // staging addresses: chunk = 1024B = 8 rows of 128B; lane covers 16B
    int lr = lane >> 3, lc = (lane & 7) * 8;  // row-in-chunk, col elem
    const __bf16* gA[4];
#pragma unroll
    for (int j = 0; j < 4; j++) {
        int c = w * 4 + j;
        int row = c * 8 + lr;
        int tok = pair_token[mb * MBLK + row];
        gA[j] = xb + (size_t)tok * DDIM + lc;
    }
    const __bf16* gG[2]; const __bf16* gU[2];
#pragma unroll
    for (int j = 0; j < 2; j++) {
        int c = w * 2 + j;
        int row = c * 8 + lr;
        gG[j] = G + (size_t)(hbase + row) * DDIM + lc;
        gU[j] = U + (size_t)(hbase + row) * DDIM + lc;
    }

    f32x4 accg[4][2], accu[4][2];
#pragma unroll
    for (int m = 0; m < 4; m++)
#pragma unroll
        for (int n = 0; n < 2; n++) { accg[m][n] = (f32x4)0.0f; accu[m][n] = (f32x4)0.0f; }

    for (int kk = 0; kk < DDIM; kk += 64) {
#pragma unroll
        for (int j = 0; j < 4; j++) {
            int c = w * 4 + j;
            GLOAD16(gA[j] + kk, &As[c * 512 + lane * 8]);
        }
#pragma unroll
        for (int j = 0; j < 2; j++) {
            int c = w * 2 + j;
            GLOAD16(gG[j] + kk, &Bg[c * 512 + lane * 8]);
            GLOAD16(gU[j] + kk, &Bu[c * 512 + lane * 8]);
        }
        __syncthreads();   // drains vmcnt before reads

#pragma unroll
        for (int ks = 0; ks < 2; ks++) {
            int kb = ks * 32 + (lane >> 4) * 8;
            bf16x8 af[4];
#pragma unroll
            for (int m = 0; m < 4; m++)
                af[m] = *reinterpret_cast<const bf16x8*>(
                    &As[(wr * 64 + m * 16 + (lane & 15)) * 64 + kb]);
#pragma unroll
            for (int n = 0; n < 2; n++) {
                bf16x8 bg = *reinterpret_cast<const bf16x8*>(
                    &Bg[(wc * 32 + n * 16 + (lane & 15)) * 64 + kb]);
                bf16x8 bu = *reinterpret_cast<const bf16x8*>(
                    &Bu[(wc * 32 + n * 16 + (lane & 15)) * 64 + kb]);
#pragma unroll
                for (int m = 0; m < 4; m++) {
                    accg[m][n] = __builtin_amdgcn_mfma_f32_16x16x32_bf16(af[m], bg, accg[m][n], 0, 0, 0);
                    accu[m][n] = __builtin_amdgcn_mfma_f32_16x16x32_bf16(af[m], bu, accu[m][n], 0, 0, 0);
                }
            }
        }
        __syncthreads();
    }

    size_t slotbase = (size_t)mb * MBLK;
#pragma unroll
    for (int m = 0; m < 4; m++)
#pragma unroll
        for (int n = 0; n < 2; n++)
#pragma unroll
            for (int r = 0; r < 4; r++) {
                int row = wr * 64 + m * 16 + (lane >> 4) * 4 + r;
                int col = hbase + wc * 32 + n * 16 + (lane & 15);
                float a = accg[m][n][r], u = accu[m][n][r];
                float hv = (a / (1.0f + expf(-a))) * u;
                hbuf[(slotbase + row) * HDIM + col] = (__bf16)hv;
            }
}

// ---------------- down GEMM (m97 structure) ----------------
// Tile: 128 pairs x 64 d-cols, BK=64, K=1536. Writes f32 ybuf[slot][D].
__global__ __launch_bounds__(256) void down_kernel(
    const __bf16* __restrict__ hbuf, const __bf16* __restrict__ Dt,
    const int* __restrict__ ctrl, float* __restrict__ ybuf)
{
    int mb = blockIdx.x;
    if (mb >= ctrl[24]) return;
    int e = ctrl[32 + mb];
    int dbase = blockIdx.y * 64;
    const __bf16* Dn = Dt + (size_t)e * DDIM * HDIM;   // [D][H]

    __shared__ __bf16 As[128 * 64];   // 16 KB
    __shared__ __bf16 Bd[64 * 64];    //  8 KB

    int tid = threadIdx.x;
    int lane = tid & 63, w = tid >> 6;
    int wr = w >> 1, wc = w & 1;

    int lr = lane >> 3, lc = (lane & 7) * 8;
    const __bf16* gA[4];
#pragma unroll
    for (int j = 0; j < 4; j++) {
        int c = w * 4 + j;
        int row = c * 8 + lr;
        gA[j] = hbuf + (size_t)(mb * MBLK + row) * HDIM + lc;
    }
    const __bf16* gB[2];
#pragma unroll
    for (int j = 0; j < 2; j++) {
        int c = w * 2 + j;
        int row = c * 8 + lr;
        gB[j] = Dn + (size_t)(dbase + row) * HDIM + lc;
    }

    f32x4 acc[4][2];
#pragma unroll
    for (int m = 0; m < 4; m++)
#pragma unroll
        for (int n = 0; n < 2; n++) acc[m][n] = (f32x4)0.0f;

    for (int kk = 0; kk < HDIM; kk += 64) {
#pragma unroll
        for (int j = 0; j < 4; j++) {
            int c = w * 4 + j;
            GLOAD16(gA[j] + kk, &As[c * 512 + lane * 8]);
        }
#pragma unroll
        for (int j = 0; j < 2; j++) {
            int c = w * 2 + j;
            GLOAD16(gB[j] + kk, &Bd[c * 512 + lane * 8]);
        }
        __syncthreads();

#pragma unroll
        for (int ks = 0; ks < 2; ks++) {
            int kb = ks * 32 + (lane >> 4) * 8;
            bf16x8 af[4];
#pragma unroll
            for (int m = 0; m < 4; m++)
                af[m] = *reinterpret_cast<const bf16x8*>(
                    &As[(wr * 64 + m * 16 + (lane & 15)) * 64 + kb]);
#pragma unroll
            for (int n = 0; n < 2; n++) {
                bf16x8 bd = *reinterpret_cast<const bf16x8*>(
                    &Bd[(wc * 32 + n * 16 + (lane & 15)) * 64 + kb]);
#pragma unroll
                for (int m = 0; m < 4; m++)
                    acc[m][n] = __builtin_amdgcn_mfma_f32_16x16x32_bf16(af[m], bd, acc[m][n], 0, 0, 0);
            }
        }
        __syncthreads();
    }

#pragma unroll
    for (int m = 0; m < 4; m++)
#pragma unroll
        for (int n = 0; n < 2; n++)
#pragma unroll
            for (int r = 0; r < 4; r++) {
                int row = wr * 64 + m * 16 + (lane >> 4) * 4 + r;
                int col = dbase + wc * 32 + n * 16 + (lane & 15);
                ybuf[(size_t)(mb * MBLK + row) * DDIM + col] = acc[m][n][r];
            }
}

// combine: out[t] = w0*y[s0] + w1*y[s1]; fully overwrites d_out.
// one block per token, 192 threads x f32x4
__global__ __launch_bounds__(192) void combine_kernel(
    const float* __restrict__ ybuf, const int* __restrict__ slot_of,
    const float* __restrict__ topk_w, float* __restrict__ out)
{
    int t = blockIdx.x;
    int q = threadIdx.x;
    int s0 = slot_of[2*t], s1 = slot_of[2*t+1];
    float w0 = topk_w[2*t], w1 = topk_w[2*t+1];
    f32x4 y0 = reinterpret_cast<const f32x4*>(ybuf + (size_t)s0 * DDIM)[q];
    f32x4 y1 = reinterpret_cast<const f32x4*>(ybuf + (size_t)s1 * DDIM)[q];
    f32x4 o;
#pragma unroll
    for (int r = 0; r < 4; r++) o[r] = w0 * y0[r] + w1 * y1[r];
    reinterpret_cast<f32x4*>(out + (size_t)t * DDIM)[q] = o;
}

// ---------------- launch ----------------
extern "C" void kernel_launch(void* const* d_in, const int* in_sizes, int n_in,
                              void* d_out, int out_size, void* d_ws, size_t ws_size,
                              hipStream_t stream)
{
    if (ws_size < WS_NEEDED) return;

    const float* x      = (const float*)d_in[0];
    const float* gate_w = (const float*)d_in[1];
    const float* gbank  = (const float*)d_in[2];
    const float* ubank  = (const float*)d_in[3];
    const float* dbank  = (const float*)d_in[4];
    float* out = (float*)d_out;

    char* ws = (char*)d_ws;
    __bf16* xb   = (__bf16*)(ws + XB_OFF);
    __bf16* Gt   = (__bf16*)(ws + GT_OFF);
    __bf16* Ut   = (__bf16*)(ws + UT_OFF);
    float*  ybuf = (float*)(ws + YB_OFF);
    __bf16* Dt   = (__bf16*)(ws + DT_OFF);
    __bf16* hbuf = (__bf16*)(ws + HB_OFF);
    int*    tki  = (int*)(ws + TKI_OFF);
    float*  tkw  = (float*)(ws + TKW_OFF);
    int*    pt   = (int*)(ws + PT_OFF);
    int*    slot = (int*)(ws + SL_OFF);
    int*    ctrl = (int*)(ws + CTRL_OFF);

    convert_x_kernel<<<(NTOK * DDIM / 4 + 255) / 256, 256, 0, stream>>>(x, xb, NTOK * DDIM / 4);

    // gate_bank [E][768][1536] -> Gt [E][1536][768]
    transpose_bf16_kernel<<<dim3(HDIM/32, DDIM/32, EEXP), 256, 0, stream>>>(gbank, Gt, DDIM, HDIM);
    transpose_bf16_kernel<<<dim3(HDIM/32, DDIM/32, EEXP), 256, 0, stream>>>(ubank, Ut, DDIM, HDIM);
    // down_bank [E][1536][768] -> Dt [E][768][1536]
    transpose_bf16_kernel<<<dim3(DDIM/32, HDIM/32, EEXP), 256, 0, stream>>>(dbank, Dt, HDIM, DDIM);

    init_pairs_kernel<<<(CAP + 255) / 256, 256, 0, stream>>>(pt);
    gating_kernel<<<NTOK / 4, 256, 0, stream>>>(x, gate_w, tki, tkw);
    route_kernel<<<1, RTHREADS, 0, stream>>>(tki, ctrl, pt, slot);

    gateup_kernel<<<dim3(MAXMB, HDIM / 64), 256, 0, stream>>>(xb, Gt, Ut, ctrl, pt, hbuf);
    down_kernel<<<dim3(MAXMB, DDIM / 64), 256, 0, stream>>>(hbuf, Dt, ctrl, ybuf);
    combine_kernel<<<NTOK, 192, 0, stream>>>(ybuf, slot, tkw, out);
}

// Round 4
// 171.917 us; speedup vs baseline: 2.3029x; 1.0801x over previous
//
#include <hip/hip_runtime.h>
#include <hip/hip_bf16.h>

// Problem constants (B=2, T=2048, D=768, E=8, H=1536, K=2)
#define NTOK 4096
#define DDIM 768
#define EEXP 8
#define HDIM 1536
#define MBLK 128
#define MAXMB 72            // floor(8192/128) + 8 experts of padding
#define CAP  (MAXMB * MBLK) // 9216
#define NENT (NTOK * 2)     // 8192 routed (token,k) entries
#define RTHREADS 1024
#define EPT (NENT / RTHREADS) // 8 entries per route thread

typedef float f32x4 __attribute__((ext_vector_type(4)));
typedef __bf16 bf16x8 __attribute__((ext_vector_type(8)));
typedef __bf16 bf16x4 __attribute__((ext_vector_type(4)));

// ---------------- workspace layout (bytes) ----------------
static const size_t XB_OFF   = 0;                       // bf16 x [NTOK][D]      6,291,456
static const size_t GT_OFF   = 6291456;                 // bf16 Gt [E][H][D]    18,874,368
static const size_t UT_OFF   = GT_OFF + 18874368;       // bf16 Ut [E][H][D]    18,874,368
static const size_t YB_OFF   = GT_OFF;                  // f32 ybuf [CAP][D]    28,311,552 (aliases Gt+Ut, dead after gateup)
static const size_t DT_OFF   = UT_OFF + 18874368;       // bf16 Dt [E][D][H]    18,874,368
static const size_t HB_OFF   = DT_OFF + 18874368;       // bf16 h  [CAP][H]     28,311,552
static const size_t TKI_OFF  = HB_OFF + 28311552;       // int  topk_idx [NENT]
static const size_t TKW_OFF  = TKI_OFF + NENT*4;        // f32  topk_w   [NENT]
static const size_t PT_OFF   = TKW_OFF + NENT*4;        // int  pair_token [CAP]
static const size_t SL_OFF   = PT_OFF + CAP*4;          // int  slot_of  [NENT]
static const size_t CTRL_OFF = SL_OFF + NENT*4;
static const size_t WS_NEEDED = CTRL_OFF + 1024;

#define GLOAD16(g, l) __builtin_amdgcn_global_load_lds( \
    (const __attribute__((address_space(1))) void*)(g),  \
    (__attribute__((address_space(3))) void*)(l), 16, 0, 0)

// ---------------- small kernels ----------------

__global__ __launch_bounds__(256) void convert_x_kernel(
    const float* __restrict__ x, __bf16* __restrict__ xb, int n4)
{
    int i = blockIdx.x * 256 + threadIdx.x;
    if (i < n4) {
        f32x4 v = reinterpret_cast<const f32x4*>(x)[i];
        bf16x4 o;
        o[0] = (__bf16)v[0]; o[1] = (__bf16)v[1];
        o[2] = (__bf16)v[2]; o[3] = (__bf16)v[3];
        reinterpret_cast<bf16x4*>(xb)[i] = o;
    }
}

// transpose last two dims + convert to bf16: src [z][R][C] f32 -> dst [z][C][R] bf16
__global__ __launch_bounds__(256) void transpose_bf16_kernel(
    const float* __restrict__ src, __bf16* __restrict__ dst, int R, int C)
{
    __shared__ float tile[32][33];
    const float* s = src + (size_t)blockIdx.z * R * C;
    __bf16* d = dst + (size_t)blockIdx.z * R * C;
    int tx = threadIdx.x & 31, ty = threadIdx.x >> 5;   // 32 x 8
    int r0 = blockIdx.y * 32, c0 = blockIdx.x * 32;
#pragma unroll
    for (int j = 0; j < 4; j++)
        tile[ty + j*8][tx] = s[(size_t)(r0 + ty + j*8) * C + c0 + tx];
    __syncthreads();
#pragma unroll
    for (int j = 0; j < 4; j++)
        d[(size_t)(c0 + ty + j*8) * R + r0 + tx] = (__bf16)tile[tx][ty + j*8];
}

// one wave per token: 8 dots of length 768, softmax, top-2, normalized weights.
// NO atomics (they serialized on 8 addresses: counts derived in route_kernel).
__global__ __launch_bounds__(256) void gating_kernel(
    const float* __restrict__ x, const float* __restrict__ gw,
    int* __restrict__ topk_idx, float* __restrict__ topk_w)
{
    int lane = threadIdx.x & 63;
    int t = blockIdx.x * 4 + (threadIdx.x >> 6);
    const float* xr = x + (size_t)t * DDIM;
    float acc[EEXP];
#pragma unroll
    for (int e = 0; e < EEXP; e++) acc[e] = 0.0f;
    for (int i = 0; i < DDIM / 64; i++) {
        int d = lane + i * 64;
        float xv = xr[d];
#pragma unroll
        for (int e = 0; e < EEXP; e++) acc[e] += xv * gw[e * DDIM + d];
    }
#pragma unroll
    for (int e = 0; e < EEXP; e++) {
        for (int off = 32; off; off >>= 1) acc[e] += __shfl_xor(acc[e], off);
    }
    if (lane == 0) {
        float m = acc[0];
#pragma unroll
        for (int e = 1; e < EEXP; e++) m = fmaxf(m, acc[e]);
        float p[EEXP], sum = 0.0f;
#pragma unroll
        for (int e = 0; e < EEXP; e++) { p[e] = expf(acc[e] - m); sum += p[e]; }
        int i0 = 0; float b0 = acc[0];
#pragma unroll
        for (int e = 1; e < EEXP; e++) if (acc[e] > b0) { b0 = acc[e]; i0 = e; }
        int i1 = -1; float b1 = -3.4e38f;
#pragma unroll
        for (int e = 0; e < EEXP; e++) if (e != i0 && acc[e] > b1) { b1 = acc[e]; i1 = e; }
        float pr0 = p[i0] / sum, pr1 = p[i1] / sum;
        float den = pr0 + pr1 + 1e-8f;
        topk_idx[2*t]   = i0; topk_w[2*t]   = pr0 / den;
        topk_idx[2*t+1] = i1; topk_w[2*t+1] = pr1 / den;
    }
}

// single-block deterministic routing: zero-init pads + counts + 128-aligned
// offsets + mblock table + slot assignment via shfl/LDS prefix scans. No atomics.
__global__ __launch_bounds__(RTHREADS) void route_kernel(
    const int* __restrict__ topk_idx, int* __restrict__ ctrl,
    int* __restrict__ pair_token, int* __restrict__ slot_of)
{
    __shared__ int wt[EEXP][16];    // per-wave totals
    __shared__ int wpre[EEXP][16];  // exclusive prefix of wave totals
    __shared__ int base[EEXP];      // 128-aligned expert base slot

    int tid = threadIdx.x;
    int lane = tid & 63, wv = tid >> 6;

    // zero pad slots (poisoned ws would otherwise feed garbage token indices)
    for (int i = tid; i < CAP; i += RTHREADS) pair_token[i] = 0;

    int e_of[EPT];
    int c[EEXP];
#pragma unroll
    for (int e = 0; e < EEXP; e++) c[e] = 0;
#pragma unroll
    for (int j = 0; j < EPT; j++) {
        int e = topk_idx[tid * EPT + j];
        e_of[j] = e;
        c[e]++;
    }

    // per-expert exclusive prefix within wave + wave total
    int pre[EEXP];
#pragma unroll
    for (int e = 0; e < EEXP; e++) {
        int v = c[e];
        for (int d = 1; d < 64; d <<= 1) {
            int u = __shfl_up(v, d);
            if (lane >= d) v += u;
        }
        pre[e] = v - c[e];
        if (lane == 63) wt[e][wv] = v;
    }
    __syncthreads();

    if (tid == 0) {
        int off = 0, gmb = 0;
        for (int e = 0; e < EEXP; e++) {
            int run = 0;
            for (int w = 0; w < 16; w++) { wpre[e][w] = run; run += wt[e][w]; }
            base[e] = off;
            int nmb = (run + MBLK - 1) >> 7;
            for (int i = 0; i < nmb; i++) ctrl[32 + gmb++] = e;
            off += nmb << 7;
        }
        ctrl[24] = gmb;
    }
    __syncthreads();

    int run[EEXP];
#pragma unroll
    for (int e = 0; e < EEXP; e++) run[e] = base[e] + wpre[e][wv] + pre[e];
#pragma unroll
    for (int j = 0; j < EPT; j++) {
        int ent = tid * EPT + j;
        int e = e_of[j];
        int slot = run[e]++;
        pair_token[slot] = ent >> 1;
        slot_of[ent] = slot;
    }
}

// ---------------- gate/up fused GEMM (m97 structure, 128x128) ----------------
// Tile: 128 pairs x 128 h-cols, BK=64, K=768. 4 waves (2x2), wave tile 64x64.
// h = silu(x@G) * (x@U) stored bf16 to hbuf.
__global__ __launch_bounds__(256, 2) void gateup_kernel(
    const __bf16* __restrict__ xb, const __bf16* __restrict__ Gt,
    const __bf16* __restrict__ Ut, const int* __restrict__ ctrl,
    const int* __restrict__ pair_token, __bf16* __restrict__ hbuf)
{
    int mb = blockIdx.x;
    if (mb >= ctrl[24]) return;
    int e = ctrl[32 + mb];
    int hbase = blockIdx.y * 128;
    const __bf16* G = Gt + (size_t)e * HDIM * DDIM;   // [H][D]
    const __bf16* U = Ut + (size_t)e * HDIM * DDIM;

    __shared__ __bf16 As[128 * 64];   // 16 KB, linear [row][64k]
    __shared__ __bf16 Bg[128 * 64];   // 16 KB
    __shared__ __bf16 Bu[128 * 64];   // 16 KB

    int tid = threadIdx.x;
    int lane = tid & 63, w = tid >> 6;
    int wr = w >> 1, wc = w & 1;

    // staging: chunk = 1024B = 8 rows of 128B; lane covers 16B; 16 chunks/tile
    int lr = lane >> 3, lc = (lane & 7) * 8;  // row-in-chunk, col elem
    const __bf16* gA[4];
#pragma unroll
    for (int j = 0; j < 4; j++) {
        int row = (w * 4 + j) * 8 + lr;
        int tok = pair_token[mb * MBLK + row];
        gA[j] = xb + (size_t)tok * DDIM + lc;
    }
    const __bf16* gG = G + (size_t)(hbase + w * 32 + lr) * DDIM + lc;  // +j*8 rows
    const __bf16* gU = U + (size_t)(hbase + w * 32 + lr) * DDIM + lc;

    f32x4 accg[4][4], accu[4][4];
#pragma unroll
    for (int m = 0; m < 4; m++)
#pragma unroll
        for (int n = 0; n < 4; n++) { accg[m][n] = (f32x4)0.0f; accu[m][n] = (f32x4)0.0f; }

    for (int kk = 0; kk < DDIM; kk += 64) {
#pragma unroll
        for (int j = 0; j < 4; j++)
            GLOAD16(gA[j] + kk, &As[(w * 4 + j) * 512 + lane * 8]);
#pragma unroll
        for (int j = 0; j < 4; j++)
            GLOAD16(gG + kk + (size_t)j * 8 * DDIM, &Bg[(w * 4 + j) * 512 + lane * 8]);
#pragma unroll
        for (int j = 0; j < 4; j++)
            GLOAD16(gU + kk + (size_t)j * 8 * DDIM, &Bu[(w * 4 + j) * 512 + lane * 8]);
        __syncthreads();   // drains vmcnt before reads

#pragma unroll
        for (int ks = 0; ks < 2; ks++) {
            int kb = ks * 32 + (lane >> 4) * 8;
            bf16x8 af[4];
#pragma unroll
            for (int m = 0; m < 4; m++)
                af[m] = *reinterpret_cast<const bf16x8*>(
                    &As[(wr * 64 + m * 16 + (lane & 15)) * 64 + kb]);
#pragma unroll
            for (int n = 0; n < 4; n++) {
                bf16x8 bg = *reinterpret_cast<const bf16x8*>(
                    &Bg[(wc * 64 + n * 16 + (lane & 15)) * 64 + kb]);
                bf16x8 bu = *reinterpret_cast<const bf16x8*>(
                    &Bu[(wc * 64 + n * 16 + (lane & 15)) * 64 + kb]);
#pragma unroll
                for (int m = 0; m < 4; m++) {
                    accg[m][n] = __builtin_amdgcn_mfma_f32_16x16x32_bf16(af[m], bg, accg[m][n], 0, 0, 0);
                    accu[m][n] = __builtin_amdgcn_mfma_f32_16x16x32_bf16(af[m], bu, accu[m][n], 0, 0, 0);
                }
            }
        }
        __syncthreads();
    }

    size_t slotbase = (size_t)mb * MBLK;
#pragma unroll
    for (int m = 0; m < 4; m++)
#pragma unroll
        for (int n = 0; n < 4; n++)
#pragma unroll
            for (int r = 0; r < 4; r++) {
                int row = wr * 64 + m * 16 + (lane >> 4) * 4 + r;
                int col = hbase + wc * 64 + n * 16 + (lane & 15);
                float a = accg[m][n][r], u = accu[m][n][r];
                float hv = (a / (1.0f + expf(-a))) * u;
                hbuf[(slotbase + row) * HDIM + col] = (__bf16)hv;
            }
}

// ---------------- down GEMM (m97 structure, 128x128) ----------------
// Tile: 128 pairs x 128 d-cols, BK=64, K=1536. Writes f32 ybuf[slot][D].
__global__ __launch_bounds__(256, 2) void down_kernel(
    const __bf16* __restrict__ hbuf, const __bf16* __restrict__ Dt,
    const int* __restrict__ ctrl, float* __restrict__ ybuf)
{
    int mb = blockIdx.x;
    if (mb >= ctrl[24]) return;
    int e = ctrl[32 + mb];
    int dbase = blockIdx.y * 128;
    const __bf16* Dn = Dt + (size_t)e * DDIM * HDIM;   // [D][H]

    __shared__ __bf16 As[128 * 64];   // 16 KB
    __shared__ __bf16 Bd[128 * 64];   // 16 KB

    int tid = threadIdx.x;
    int lane = tid & 63, w = tid >> 6;
    int wr = w >> 1, wc = w & 1;

    int lr = lane >> 3, lc = (lane & 7) * 8;
    const __bf16* gA = hbuf + (size_t)(mb * MBLK + w * 32 + lr) * HDIM + lc;  // +j*8 rows
    const __bf16* gB = Dn + (size_t)(dbase + w * 32 + lr) * HDIM + lc;

    f32x4 acc[4][4];
#pragma unroll
    for (int m = 0; m < 4; m++)
#pragma unroll
        for (int n = 0; n < 4; n++) acc[m][n] = (f32x4)0.0f;

    for (int kk = 0; kk < HDIM; kk += 64) {
#pragma unroll
        for (int j = 0; j < 4; j++)
            GLOAD16(gA + kk + (size_t)j * 8 * HDIM, &As[(w * 4 + j) * 512 + lane * 8]);
#pragma unroll
        for (int j = 0; j < 4; j++)
            GLOAD16(gB + kk + (size_t)j * 8 * HDIM, &Bd[(w * 4 + j) * 512 + lane * 8]);
        __syncthreads();

#pragma unroll
        for (int ks = 0; ks < 2; ks++) {
            int kb = ks * 32 + (lane >> 4) * 8;
            bf16x8 af[4];
#pragma unroll
            for (int m = 0; m < 4; m++)
                af[m] = *reinterpret_cast<const bf16x8*>(
                    &As[(wr * 64 + m * 16 + (lane & 15)) * 64 + kb]);
#pragma unroll
            for (int n = 0; n < 4; n++) {
                bf16x8 bd = *reinterpret_cast<const bf16x8*>(
                    &Bd[(wc * 64 + n * 16 + (lane & 15)) * 64 + kb]);
#pragma unroll
                for (int m = 0; m < 4; m++)
                    acc[m][n] = __builtin_amdgcn_mfma_f32_16x16x32_bf16(af[m], bd, acc[m][n], 0, 0, 0);
            }
        }
        __syncthreads();
    }

#pragma unroll
    for (int m = 0; m < 4; m++)
#pragma unroll
        for (int n = 0; n < 4; n++)
#pragma unroll
            for (int r = 0; r < 4; r++) {
                int row = wr * 64 + m * 16 + (lane >> 4) * 4 + r;
                int col = dbase + wc * 64 + n * 16 + (lane & 15);
                ybuf[(size_t)(mb * MBLK + row) * DDIM + col] = acc[m][n][r];
            }
}

// combine: out[t] = w0*y[s0] + w1*y[s1]; fully overwrites d_out.
// one block per token, 192 threads x f32x4
__global__ __launch_bounds__(192) void combine_kernel(
    const float* __restrict__ ybuf, const int* __restrict__ slot_of,
    const float* __restrict__ topk_w, float* __restrict__ out)
{
    int t = blockIdx.x;
    int q = threadIdx.x;
    int s0 = slot_of[2*t], s1 = slot_of[2*t+1];
    float w0 = topk_w[2*t], w1 = topk_w[2*t+1];
    f32x4 y0 = reinterpret_cast<const f32x4*>(ybuf + (size_t)s0 * DDIM)[q];
    f32x4 y1 = reinterpret_cast<const f32x4*>(ybuf + (size_t)s1 * DDIM)[q];
    f32x4 o;
#pragma unroll
    for (int r = 0; r < 4; r++) o[r] = w0 * y0[r] + w1 * y1[r];
    reinterpret_cast<f32x4*>(out + (size_t)t * DDIM)[q] = o;
}

// ---------------- launch ----------------
extern "C" void kernel_launch(void* const* d_in, const int* in_sizes, int n_in,
                              void* d_out, int out_size, void* d_ws, size_t ws_size,
                              hipStream_t stream)
{
    if (ws_size < WS_NEEDED) return;

    const float* x      = (const float*)d_in[0];
    const float* gate_w = (const float*)d_in[1];
    const float* gbank  = (const float*)d_in[2];
    const float* ubank  = (const float*)d_in[3];
    const float* dbank  = (const float*)d_in[4];
    float* out = (float*)d_out;

    char* ws = (char*)d_ws;
    __bf16* xb   = (__bf16*)(ws + XB_OFF);
    __bf16* Gt   = (__bf16*)(ws + GT_OFF);
    __bf16* Ut   = (__bf16*)(ws + UT_OFF);
    float*  ybuf = (float*)(ws + YB_OFF);
    __bf16* Dt   = (__bf16*)(ws + DT_OFF);
    __bf16* hbuf = (__bf16*)(ws + HB_OFF);
    int*    tki  = (int*)(ws + TKI_OFF);
    float*  tkw  = (float*)(ws + TKW_OFF);
    int*    pt   = (int*)(ws + PT_OFF);
    int*    slot = (int*)(ws + SL_OFF);
    int*    ctrl = (int*)(ws + CTRL_OFF);

    convert_x_kernel<<<(NTOK * DDIM / 4 + 255) / 256, 256, 0, stream>>>(x, xb, NTOK * DDIM / 4);

    // gate_bank [E][768][1536] -> Gt [E][1536][768]
    transpose_bf16_kernel<<<dim3(HDIM/32, DDIM/32, EEXP), 256, 0, stream>>>(gbank, Gt, DDIM, HDIM);
    transpose_bf16_kernel<<<dim3(HDIM/32, DDIM/32, EEXP), 256, 0, stream>>>(ubank, Ut, DDIM, HDIM);
    // down_bank [E][1536][768] -> Dt [E][768][1536]
    transpose_bf16_kernel<<<dim3(DDIM/32, HDIM/32, EEXP), 256, 0, stream>>>(dbank, Dt, HDIM, DDIM);

    gating_kernel<<<NTOK / 4, 256, 0, stream>>>(x, gate_w, tki, tkw);
    route_kernel<<<1, RTHREADS, 0, stream>>>(tki, ctrl, pt, slot);

    gateup_kernel<<<dim3(MAXMB, HDIM / 128), 256, 0, stream>>>(xb, Gt, Ut, ctrl, pt, hbuf);
    down_kernel<<<dim3(MAXMB, DDIM / 128), 256, 0, stream>>>(hbuf, Dt, ctrl, ybuf);
    combine_kernel<<<NTOK, 192, 0, stream>>>(ybuf, slot, tkw, out);
}

// Round 5
// 149.557 us; speedup vs baseline: 2.6472x; 1.1495x over previous
//
#include <hip/hip_runtime.h>
#include <hip/hip_bf16.h>

// Problem constants (B=2, T=2048, D=768, E=8, H=1536, K=2)
#define NTOK 4096
#define DDIM 768
#define EEXP 8
#define HDIM 1536
#define MBLK 128
#define MAXMB 72            // sum ceil(cnt_e/128) <= 64+7, +margin
#define CAP  (MAXMB * MBLK) // 9216
#define NENT (NTOK * 2)     // 8192 routed (token,k) entries
#define RTHREADS 1024
#define EPT (NENT / RTHREADS) // 8 entries per route thread

typedef float f32x4 __attribute__((ext_vector_type(4)));
typedef __bf16 bf16x8 __attribute__((ext_vector_type(8)));
typedef __bf16 bf16x4 __attribute__((ext_vector_type(4)));

// ---------------- workspace layout (bytes) ----------------
static const size_t XB_OFF   = 0;                       // bf16 x [NTOK][D]      6,291,456
static const size_t GT_OFF   = 6291456;                 // bf16 Gt [E][H][D]    18,874,368
static const size_t UT_OFF   = GT_OFF + 18874368;       // bf16 Ut [E][H][D]    18,874,368
static const size_t YB_OFF   = GT_OFF;                  // f32 ybuf [CAP][D]    28,311,552 (aliases Gt+Ut, dead after gateup)
static const size_t DT_OFF   = UT_OFF + 18874368;       // bf16 Dt [E][D][H]    18,874,368
static const size_t HB_OFF   = DT_OFF + 18874368;       // bf16 h  [CAP][H]     28,311,552
static const size_t TKI_OFF  = HB_OFF + 28311552;       // int  topk_idx [NENT]
static const size_t TKW_OFF  = TKI_OFF + NENT*4;        // f32  topk_w   [NENT]
static const size_t PT_OFF   = TKW_OFF + NENT*4;        // int  pair_token [CAP]
static const size_t SL_OFF   = PT_OFF + CAP*4;          // int  slot_of  [NENT]
static const size_t CTRL_OFF = SL_OFF + NENT*4;
static const size_t WS_NEEDED = CTRL_OFF + 1024;

#define GLOAD16(g, l) __builtin_amdgcn_global_load_lds( \
    (const __attribute__((address_space(1))) void*)(g),  \
    (__attribute__((address_space(3))) void*)(l), 16, 0, 0)

// T2 swizzle: LDS tile rows are 64 bf16 (128 B). Fragment reads hit 16 rows at
// 128B stride = same bank (16-way). XOR the 16B-group index with (row&7):
// read addr = row*64 + (kb ^ ((row&7)<<3)); the global SOURCE column is
// pre-swizzled identically so gload_lds's linear write lands data there.

// ---------------- small kernels ----------------

__global__ __launch_bounds__(256) void convert_x_kernel(
    const float* __restrict__ x, __bf16* __restrict__ xb, int n4)
{
    int i = blockIdx.x * 256 + threadIdx.x;
    if (i < n4) {
        f32x4 v = reinterpret_cast<const f32x4*>(x)[i];
        bf16x4 o;
        o[0] = (__bf16)v[0]; o[1] = (__bf16)v[1];
        o[2] = (__bf16)v[2]; o[3] = (__bf16)v[3];
        reinterpret_cast<bf16x4*>(xb)[i] = o;
    }
}

// transpose last two dims + convert to bf16: src [z][R][C] f32 -> dst [z][C][R] bf16
__global__ __launch_bounds__(256) void transpose_bf16_kernel(
    const float* __restrict__ src, __bf16* __restrict__ dst, int R, int C)
{
    __shared__ float tile[32][33];
    const float* s = src + (size_t)blockIdx.z * R * C;
    __bf16* d = dst + (size_t)blockIdx.z * R * C;
    int tx = threadIdx.x & 31, ty = threadIdx.x >> 5;   // 32 x 8
    int r0 = blockIdx.y * 32, c0 = blockIdx.x * 32;
#pragma unroll
    for (int j = 0; j < 4; j++)
        tile[ty + j*8][tx] = s[(size_t)(r0 + ty + j*8) * C + c0 + tx];
    __syncthreads();
#pragma unroll
    for (int j = 0; j < 4; j++)
        d[(size_t)(c0 + ty + j*8) * R + r0 + tx] = (__bf16)tile[tx][ty + j*8];
}

// one wave per token: 8 dots of length 768, softmax, top-2, normalized weights.
// NO atomics (8-address atomic contention serialized the whole kernel).
__global__ __launch_bounds__(256) void gating_kernel(
    const float* __restrict__ x, const float* __restrict__ gw,
    int* __restrict__ topk_idx, float* __restrict__ topk_w)
{
    int lane = threadIdx.x & 63;
    int t = blockIdx.x * 4 + (threadIdx.x >> 6);
    const float* xr = x + (size_t)t * DDIM;
    float acc[EEXP];
#pragma unroll
    for (int e = 0; e < EEXP; e++) acc[e] = 0.0f;
    for (int i = 0; i < DDIM / 64; i++) {
        int d = lane + i * 64;
        float xv = xr[d];
#pragma unroll
        for (int e = 0; e < EEXP; e++) acc[e] += xv * gw[e * DDIM + d];
    }
#pragma unroll
    for (int e = 0; e < EEXP; e++) {
        for (int off = 32; off; off >>= 1) acc[e] += __shfl_xor(acc[e], off);
    }
    if (lane == 0) {
        float m = acc[0];
#pragma unroll
        for (int e = 1; e < EEXP; e++) m = fmaxf(m, acc[e]);
        float p[EEXP], sum = 0.0f;
#pragma unroll
        for (int e = 0; e < EEXP; e++) { p[e] = expf(acc[e] - m); sum += p[e]; }
        int i0 = 0; float b0 = acc[0];
#pragma unroll
        for (int e = 1; e < EEXP; e++) if (acc[e] > b0) { b0 = acc[e]; i0 = e; }
        int i1 = -1; float b1 = -3.4e38f;
#pragma unroll
        for (int e = 0; e < EEXP; e++) if (e != i0 && acc[e] > b1) { b1 = acc[e]; i1 = e; }
        float pr0 = p[i0] / sum, pr1 = p[i1] / sum;
        float den = pr0 + pr1 + 1e-8f;
        topk_idx[2*t]   = i0; topk_w[2*t]   = pr0 / den;
        topk_idx[2*t+1] = i1; topk_w[2*t+1] = pr1 / den;
    }
}

// single-block deterministic routing: zero-init pads + counts + 128-aligned
// offsets + mblock table + slot assignment via shfl/LDS prefix scans. No atomics.
__global__ __launch_bounds__(RTHREADS) void route_kernel(
    const int* __restrict__ topk_idx, int* __restrict__ ctrl,
    int* __restrict__ pair_token, int* __restrict__ slot_of)
{
    __shared__ int wt[EEXP][16];    // per-wave totals
    __shared__ int wpre[EEXP][16];  // exclusive prefix of wave totals
    __shared__ int base[EEXP];      // 128-aligned expert base slot

    int tid = threadIdx.x;
    int lane = tid & 63, wv = tid >> 6;

    // zero pad slots (poisoned ws would otherwise feed garbage token indices)
    for (int i = tid; i < CAP; i += RTHREADS) pair_token[i] = 0;

    int e_of[EPT];
    int c[EEXP];
#pragma unroll
    for (int e = 0; e < EEXP; e++) c[e] = 0;
#pragma unroll
    for (int j = 0; j < EPT; j++) {
        int e = topk_idx[tid * EPT + j];
        e_of[j] = e;
        c[e]++;
    }

    // per-expert exclusive prefix within wave + wave total
    int pre[EEXP];
#pragma unroll
    for (int e = 0; e < EEXP; e++) {
        int v = c[e];
        for (int d = 1; d < 64; d <<= 1) {
            int u = __shfl_up(v, d);
            if (lane >= d) v += u;
        }
        pre[e] = v - c[e];
        if (lane == 63) wt[e][wv] = v;
    }
    __syncthreads();

    if (tid == 0) {
        int off = 0, gmb = 0;
        for (int e = 0; e < EEXP; e++) {
            int run = 0;
            for (int w = 0; w < 16; w++) { wpre[e][w] = run; run += wt[e][w]; }
            base[e] = off;
            int nmb = (run + MBLK - 1) >> 7;
            for (int i = 0; i < nmb; i++) ctrl[32 + gmb++] = e;
            off += nmb << 7;
        }
        ctrl[24] = gmb;
    }
    __syncthreads();

    int run[EEXP];
#pragma unroll
    for (int e = 0; e < EEXP; e++) run[e] = base[e] + wpre[e][wv] + pre[e];
#pragma unroll
    for (int j = 0; j < EPT; j++) {
        int ent = tid * EPT + j;
        int e = e_of[j];
        int slot = run[e]++;
        pair_token[slot] = ent >> 1;
        slot_of[ent] = slot;
    }
}

// ---------------- gate/up fused GEMM (dbuf 2-phase + T2 swizzle) ----------------
// Tile: 128 pairs x 128 h-cols, BK=64, K=768. 512 threads = 8 waves (2x4),
// wave tile 64x32. LDS: 2 x (A 16K + Bg 16K + Bu 16K) = 96 KB (1 block/CU).
__global__ __launch_bounds__(512, 2) void gateup_kernel(
    const __bf16* __restrict__ xb, const __bf16* __restrict__ Gt,
    const __bf16* __restrict__ Ut, const int* __restrict__ ctrl,
    const int* __restrict__ pair_token, __bf16* __restrict__ hbuf)
{
    // flattened grid, y-fastest; bijective XCD chunk swizzle (864 % 8 == 0)
    int bid = blockIdx.x;
    int swz = (bid & 7) * (MAXMB * 12 / 8) + (bid >> 3);
    int mb = swz / 12, y = swz - mb * 12;
    if (mb >= ctrl[24]) return;
    int e = ctrl[32 + mb];
    int hbase = y * 128;
    const __bf16* G = Gt + (size_t)e * HDIM * DDIM;   // [H][D]
    const __bf16* U = Ut + (size_t)e * HDIM * DDIM;

    __shared__ __bf16 lds[2 * 3 * 8192];   // 96 KB: [buf][A|Bg|Bu][128*64]

    int tid = threadIdx.x;
    int lane = tid & 63, w = tid >> 6;
    int wr = w >> 2, wc = w & 3;

    // staging: each load = 512 thr x 16B = one 64-row x 64-col chunk.
    // source col pre-swizzled so linear LDS write realizes the XOR layout.
    int lr = tid >> 3;                                 // row in chunk, 0..63
    int lc = ((tid & 7) ^ (lr & 7)) << 3;              // swizzled col elem
    int tok0 = pair_token[mb * MBLK + lr];
    int tok1 = pair_token[mb * MBLK + 64 + lr];
    const __bf16* gA0 = xb + (size_t)tok0 * DDIM + lc;
    const __bf16* gA1 = xb + (size_t)tok1 * DDIM + lc;
    const __bf16* gG0 = G + (size_t)(hbase + lr) * DDIM + lc;
    const __bf16* gU0 = U + (size_t)(hbase + lr) * DDIM + lc;
    const size_t bstep = (size_t)64 * DDIM;            // +64 B-rows

    f32x4 accg[4][2], accu[4][2];
#pragma unroll
    for (int m = 0; m < 4; m++)
#pragma unroll
        for (int n = 0; n < 2; n++) { accg[m][n] = (f32x4)0.0f; accu[m][n] = (f32x4)0.0f; }

    // prologue: stage tile 0 into buf 0
    {
        __bf16* d = &lds[0];
        GLOAD16(gA0, d + tid * 8);
        GLOAD16(gA1, d + 4096 + tid * 8);
        GLOAD16(gG0, d + 8192 + tid * 8);
        GLOAD16(gG0 + bstep, d + 12288 + tid * 8);
        GLOAD16(gU0, d + 16384 + tid * 8);
        GLOAD16(gU0 + bstep, d + 20480 + tid * 8);
    }
    __syncthreads();

    int cur = 0;
    for (int t = 0; t < DDIM / 64; ++t) {
        if (t < DDIM / 64 - 1) {           // prefetch next K-tile into other buf
            int kk = (t + 1) * 64;
            __bf16* d = &lds[(cur ^ 1) * 24576];
            GLOAD16(gA0 + kk, d + tid * 8);
            GLOAD16(gA1 + kk, d + 4096 + tid * 8);
            GLOAD16(gG0 + kk, d + 8192 + tid * 8);
            GLOAD16(gG0 + kk + bstep, d + 12288 + tid * 8);
            GLOAD16(gU0 + kk, d + 16384 + tid * 8);
            GLOAD16(gU0 + kk + bstep, d + 20480 + tid * 8);
        }
        const __bf16* A  = &lds[cur * 24576];
        const __bf16* Bg = A + 8192;
        const __bf16* Bu = A + 16384;
#pragma unroll
        for (int ks = 0; ks < 2; ks++) {
            int kb = ks * 32 + (lane >> 4) * 8;
            bf16x8 af[4];
#pragma unroll
            for (int m = 0; m < 4; m++) {
                int row = wr * 64 + m * 16 + (lane & 15);
                af[m] = *reinterpret_cast<const bf16x8*>(
                    &A[row * 64 + (kb ^ ((row & 7) << 3))]);
            }
#pragma unroll
            for (int n = 0; n < 2; n++) {
                int col = wc * 32 + n * 16 + (lane & 15);
                int ba = col * 64 + (kb ^ ((col & 7) << 3));
                bf16x8 bg = *reinterpret_cast<const bf16x8*>(&Bg[ba]);
                bf16x8 bu = *reinterpret_cast<const bf16x8*>(&Bu[ba]);
#pragma unroll
                for (int m = 0; m < 4; m++) {
                    accg[m][n] = __builtin_amdgcn_mfma_f32_16x16x32_bf16(af[m], bg, accg[m][n], 0, 0, 0);
                    accu[m][n] = __builtin_amdgcn_mfma_f32_16x16x32_bf16(af[m], bu, accu[m][n], 0, 0, 0);
                }
            }
        }
        __syncthreads();   // drains this iter's gloads (vmcnt) + lds reads (lgkm)
        cur ^= 1;
    }

    size_t slotbase = (size_t)mb * MBLK;
#pragma unroll
    for (int m = 0; m < 4; m++)
#pragma unroll
        for (int n = 0; n < 2; n++)
#pragma unroll
            for (int r = 0; r < 4; r++) {
                int row = wr * 64 + m * 16 + (lane >> 4) * 4 + r;
                int col = hbase + wc * 32 + n * 16 + (lane & 15);
                float a = accg[m][n][r], u = accu[m][n][r];
                float hv = (a / (1.0f + expf(-a))) * u;
                hbuf[(slotbase + row) * HDIM + col] = (__bf16)hv;
            }
}

// ---------------- down GEMM (dbuf 2-phase + T2 swizzle) ----------------
// Tile: 128 pairs x 128 d-cols, BK=64, K=1536. 512 thr, 8 waves (2x4).
// LDS: 2 x (A 16K + B 16K) = 64 KB (2 blocks/CU). Writes f32 ybuf[slot][D].
__global__ __launch_bounds__(512, 4) void down_kernel(
    const __bf16* __restrict__ hbuf, const __bf16* __restrict__ Dt,
    const int* __restrict__ ctrl, float* __restrict__ ybuf)
{
    int bid = blockIdx.x;
    int swz = (bid & 7) * (MAXMB * 6 / 8) + (bid >> 3);   // 432 % 8 == 0
    int mb = swz / 6, y = swz - mb * 6;
    if (mb >= ctrl[24]) return;
    int e = ctrl[32 + mb];
    int dbase = y * 128;
    const __bf16* Dn = Dt + (size_t)e * DDIM * HDIM;   // [D][H]

    __shared__ __bf16 lds[2 * 2 * 8192];   // 64 KB: [buf][A|B][128*64]

    int tid = threadIdx.x;
    int lane = tid & 63, w = tid >> 6;
    int wr = w >> 2, wc = w & 3;

    int lr = tid >> 3;
    int lc = ((tid & 7) ^ (lr & 7)) << 3;
    const __bf16* gA0 = hbuf + (size_t)(mb * MBLK + lr) * HDIM + lc;
    const __bf16* gB0 = Dn + (size_t)(dbase + lr) * HDIM + lc;
    const size_t astep = (size_t)64 * HDIM;

    f32x4 acc[4][2];
#pragma unroll
    for (int m = 0; m < 4; m++)
#pragma unroll
        for (int n = 0; n < 2; n++) acc[m][n] = (f32x4)0.0f;

    {
        __bf16* d = &lds[0];
        GLOAD16(gA0, d + tid * 8);
        GLOAD16(gA0 + astep, d + 4096 + tid * 8);
        GLOAD16(gB0, d + 8192 + tid * 8);
        GLOAD16(gB0 + astep, d + 12288 + tid * 8);
    }
    __syncthreads();

    int cur = 0;
    for (int t = 0; t < HDIM / 64; ++t) {
        if (t < HDIM / 64 - 1) {
            int kk = (t + 1) * 64;
            __bf16* d = &lds[(cur ^ 1) * 16384];
            GLOAD16(gA0 + kk, d + tid * 8);
            GLOAD16(gA0 + kk + astep, d + 4096 + tid * 8);
            GLOAD16(gB0 + kk, d + 8192 + tid * 8);
            GLOAD16(gB0 + kk + astep, d + 12288 + tid * 8);
        }
        const __bf16* A = &lds[cur * 16384];
        const __bf16* B = A + 8192;
#pragma unroll
        for (int ks = 0; ks < 2; ks++) {
            int kb = ks * 32 + (lane >> 4) * 8;
            bf16x8 af[4];
#pragma unroll
            for (int m = 0; m < 4; m++) {
                int row = wr * 64 + m * 16 + (lane & 15);
                af[m] = *reinterpret_cast<const bf16x8*>(
                    &A[row * 64 + (kb ^ ((row & 7) << 3))]);
            }
#pragma unroll
            for (int n = 0; n < 2; n++) {
                int col = wc * 32 + n * 16 + (lane & 15);
                bf16x8 bd = *reinterpret_cast<const bf16x8*>(
                    &B[col * 64 + (kb ^ ((col & 7) << 3))]);
#pragma unroll
                for (int m = 0; m < 4; m++)
                    acc[m][n] = __builtin_amdgcn_mfma_f32_16x16x32_bf16(af[m], bd, acc[m][n], 0, 0, 0);
            }
        }
        __syncthreads();
        cur ^= 1;
    }

#pragma unroll
    for (int m = 0; m < 4; m++)
#pragma unroll
        for (int n = 0; n < 2; n++)
#pragma unroll
            for (int r = 0; r < 4; r++) {
                int row = wr * 64 + m * 16 + (lane >> 4) * 4 + r;
                int col = dbase + wc * 32 + n * 16 + (lane & 15);
                ybuf[(size_t)(mb * MBLK + row) * DDIM + col] = acc[m][n][r];
            }
}

// combine: out[t] = w0*y[s0] + w1*y[s1]; fully overwrites d_out.
__global__ __launch_bounds__(192) void combine_kernel(
    const float* __restrict__ ybuf, const int* __restrict__ slot_of,
    const float* __restrict__ topk_w, float* __restrict__ out)
{
    int t = blockIdx.x;
    int q = threadIdx.x;
    int s0 = slot_of[2*t], s1 = slot_of[2*t+1];
    float w0 = topk_w[2*t], w1 = topk_w[2*t+1];
    f32x4 y0 = reinterpret_cast<const f32x4*>(ybuf + (size_t)s0 * DDIM)[q];
    f32x4 y1 = reinterpret_cast<const f32x4*>(ybuf + (size_t)s1 * DDIM)[q];
    f32x4 o;
#pragma unroll
    for (int r = 0; r < 4; r++) o[r] = w0 * y0[r] + w1 * y1[r];
    reinterpret_cast<f32x4*>(out + (size_t)t * DDIM)[q] = o;
}

// ---------------- launch ----------------
extern "C" void kernel_launch(void* const* d_in, const int* in_sizes, int n_in,
                              void* d_out, int out_size, void* d_ws, size_t ws_size,
                              hipStream_t stream)
{
    if (ws_size < WS_NEEDED) return;

    const float* x      = (const float*)d_in[0];
    const float* gate_w = (const float*)d_in[1];
    const float* gbank  = (const float*)d_in[2];
    const float* ubank  = (const float*)d_in[3];
    const float* dbank  = (const float*)d_in[4];
    float* out = (float*)d_out;

    char* ws = (char*)d_ws;
    __bf16* xb   = (__bf16*)(ws + XB_OFF);
    __bf16* Gt   = (__bf16*)(ws + GT_OFF);
    __bf16* Ut   = (__bf16*)(ws + UT_OFF);
    float*  ybuf = (float*)(ws + YB_OFF);
    __bf16* Dt   = (__bf16*)(ws + DT_OFF);
    __bf16* hbuf = (__bf16*)(ws + HB_OFF);
    int*    tki  = (int*)(ws + TKI_OFF);
    float*  tkw  = (float*)(ws + TKW_OFF);
    int*    pt   = (int*)(ws + PT_OFF);
    int*    slot = (int*)(ws + SL_OFF);
    int*    ctrl = (int*)(ws + CTRL_OFF);

    convert_x_kernel<<<(NTOK * DDIM / 4 + 255) / 256, 256, 0, stream>>>(x, xb, NTOK * DDIM / 4);

    // gate_bank [E][768][1536] -> Gt [E][1536][768]
    transpose_bf16_kernel<<<dim3(HDIM/32, DDIM/32, EEXP), 256, 0, stream>>>(gbank, Gt, DDIM, HDIM);
    transpose_bf16_kernel<<<dim3(HDIM/32, DDIM/32, EEXP), 256, 0, stream>>>(ubank, Ut, DDIM, HDIM);
    // down_bank [E][1536][768] -> Dt [E][768][1536]
    transpose_bf16_kernel<<<dim3(DDIM/32, HDIM/32, EEXP), 256, 0, stream>>>(dbank, Dt, HDIM, DDIM);

    gating_kernel<<<NTOK / 4, 256, 0, stream>>>(x, gate_w, tki, tkw);
    route_kernel<<<1, RTHREADS, 0, stream>>>(tki, ctrl, pt, slot);

    gateup_kernel<<<MAXMB * (HDIM / 128), 512, 0, stream>>>(xb, Gt, Ut, ctrl, pt, hbuf);
    down_kernel<<<MAXMB * (DDIM / 128), 512, 0, stream>>>(hbuf, Dt, ctrl, ybuf);
    combine_kernel<<<NTOK, 192, 0, stream>>>(ybuf, slot, tkw, out);
}